// Round 13
// baseline (286.982 us; speedup 1.0000x reference)
//
#include <hip/hip_runtime.h>

typedef unsigned short u16;
typedef __bf16 bf16x8 __attribute__((ext_vector_type(8)));
typedef float f32x4 __attribute__((ext_vector_type(4)));
typedef float f32x16 __attribute__((ext_vector_type(16)));
typedef unsigned int u32x4 __attribute__((ext_vector_type(4)));
typedef unsigned int u32x2 __attribute__((ext_vector_type(2)));

__device__ __forceinline__ u16 f2b(float f) {
  union { float f; unsigned u; } v; v.f = f;
  return (u16)((v.u + 0x7fffu + ((v.u >> 16) & 1u)) >> 16);
}

__device__ __forceinline__ unsigned pkbf(float a, float b) {
#if __has_builtin(__builtin_amdgcn_cvt_pk_bf16_f32)
  typedef __bf16 bf16x2v __attribute__((ext_vector_type(2)));
  bf16x2v r = __builtin_amdgcn_cvt_pk_bf16_f32(a, b);
  return __builtin_bit_cast(unsigned, r);
#else
  // round-half-up (vs RNE: differs only on exact ties, <=1 ulp) + byte-perm pack: 3 VALU ops
  unsigned ua = __builtin_bit_cast(unsigned, a) + 0x8000u;
  unsigned ub = __builtin_bit_cast(unsigned, b) + 0x8000u;
  return __builtin_amdgcn_perm(ub, ua, 0x07060302u);
#endif
}

__device__ __forceinline__ float fexp2(float x) {
#if __has_builtin(__builtin_amdgcn_exp2f)
  return __builtin_amdgcn_exp2f(x);
#else
  return exp2f(x);
#endif
}

__device__ __forceinline__ bf16x8 ldfrag(const u16* p) {
  u32x4 r = *(const u32x4*)p;
  return __builtin_bit_cast(bf16x8, r);
}

// v_permlane32_swap_b32 dst, src: post dst = [dst_lo ; src_lo], src = [dst_hi ; src_hi].
__device__ __forceinline__ void plswap(unsigned& dst, unsigned& src) {
  asm("v_permlane32_swap_b32 %0, %1" : "+v"(dst), "+v"(src));
}

__device__ __forceinline__ float sum16(const f32x16& v) {
  float a = (v[0] + v[1]) + (v[2] + v[3]);
  float b = (v[4] + v[5]) + (v[6] + v[7]);
  float c = (v[8] + v[9]) + (v[10] + v[11]);
  float d = (v[12] + v[13]) + (v[14] + v[15]);
  return (a + b) + (c + d);
}

// T12: S^T C/D regs (key=(r&3)+8*(r>>2)+4*hi, q=l31) -> PV B-operand frags
// (key=ks*16+hi*8+j, q=l31) fully in-register.
__device__ __forceinline__ void build_frags(const f32x16& sc, bf16x8& fLo, bf16x8& fHi) {
  unsigned a0 = pkbf(sc[0], sc[1]);
  unsigned a1 = pkbf(sc[2], sc[3]);
  unsigned b0 = pkbf(sc[4], sc[5]);
  unsigned b1 = pkbf(sc[6], sc[7]);
  plswap(a0, b0);  // a0 = word0, b0 = word2
  plswap(a1, b1);  // a1 = word1, b1 = word3
  u32x4 f; f[0] = a0; f[1] = a1; f[2] = b0; f[3] = b1;
  fLo = __builtin_bit_cast(bf16x8, f);
  unsigned c0 = pkbf(sc[8], sc[9]);
  unsigned c1 = pkbf(sc[10], sc[11]);
  unsigned d0 = pkbf(sc[12], sc[13]);
  unsigned d1 = pkbf(sc[14], sc[15]);
  plswap(c0, d0);
  plswap(c1, d1);
  u32x4 g; g[0] = c0; g[1] = c1; g[2] = d0; g[3] = d1;
  fHi = __builtin_bit_cast(bf16x8, g);
}

#define GLOAD_LDS16(gp, lp)                                                        \
  __builtin_amdgcn_global_load_lds((const __attribute__((address_space(1))) void*)(gp), \
                                   (__attribute__((address_space(3))) void*)(lp), 16, 0, 0)

#define MFMA32(a, b, c) __builtin_amdgcn_mfma_f32_32x32x16_bf16((a), (b), (c), 0, 0, 0)

// 0.125 * log2(e): folded into Q during GEMM1 (no-max softmax in exp2 domain).
#define QSC 0.18033688011f

// ---------------- merged pack kernel ----------------

__global__ __launch_bounds__(256) void k_pack(const float* __restrict__ x,
                                              const float* __restrict__ Wq,
                                              const float* __restrict__ Wk,
                                              const float* __restrict__ Wv,
                                              const float* __restrict__ Wo,
                                              u16* __restrict__ xb,
                                              u16* __restrict__ wqkv,
                                              u16* __restrict__ wo_t) {
  const int bid = blockIdx.x, tid = threadIdx.x;
  if (bid < 4096) {
    int i = (bid * 256 + tid) * 8;
    float4 v0 = *(const float4*)(x + i);
    float4 v1 = *(const float4*)(x + i + 4);
    u32x4 o;
    o[0] = pkbf(v0.x, v0.y);
    o[1] = pkbf(v0.z, v0.w);
    o[2] = pkbf(v1.x, v1.y);
    o[3] = pkbf(v1.z, v1.w);
    *(u32x4*)(xb + i) = o;
    return;
  }
  __shared__ u16 tile[64][65];
  if (bid < 4864) {
    int b2 = bid - 4096;
    int p = b2 >> 8, rem = b2 & 255, h = rem >> 4, dt = rem & 15;
    const float* W = (p == 0) ? Wq : (p == 1) ? Wk : Wv;
    for (int i = tid; i < 4096; i += 256) {
      int d = i >> 6, e = i & 63;
      tile[e][d] = f2b(W[h * 65536 + (dt * 64 + d) * 64 + e]);
    }
    __syncthreads();
    for (int i = tid; i < 4096; i += 256) {
      int e = i >> 6, d = i & 63;
      wqkv[(size_t)(p * 1024 + h * 64 + e) * 1024 + dt * 64 + d] = tile[e][d];
    }
  } else {
    int b2 = bid - 4864;
    int kt = b2 >> 4, nt = b2 & 15;
    for (int i = tid; i < 4096; i += 256) {
      int dk = i >> 6, de = i & 63;
      tile[de][dk] = f2b(Wo[(size_t)(kt * 64 + dk) * 1024 + nt * 64 + de]);
    }
    __syncthreads();
    for (int i = tid; i < 4096; i += 256) {
      int de = i >> 6, dk = i & 63;
      wo_t[(size_t)(nt * 64 + de) * 1024 + kt * 64 + dk] = tile[de][dk];
    }
  }
}

// ---------------- GEMM core v4 (MFMA32): 128x128 tile, BK=32, 4-deep counted-vmcnt -------
// R13: the T4 mechanism in minimal form. BK=32, FOUR LDS buffers (4 x 8KB x {A,B} = 64KB,
// same 2 blocks/CU as BK=64), loads issued 2 iterations ahead, raw s_barrier +
// s_waitcnt vmcnt(8) — never 0 in the main loop (8 = the 2 younger iters' 4 loads each;
// FIFO vmcnt retirement => step-k's loads drained). Race-freedom: 1 barrier/iter bounds
// wave skew <1 iter, so concurrent reads span bufs {k-1,k,k+1} while writes target k+2 —
// distinct mod 4; each wave's own vmcnt wait certifies its staged segment pre-barrier.
// Epilogue peels iters 30/31 with vmcnt(4)/vmcnt(0). T2 swizzle = R2's verified BK=32 form.
// NOTE: do NOT add a second __launch_bounds__ arg (R5: waves-per-eu=4 budgeted 64 regs
// and spilled acc => 186us).

#define PIPE_WAIT(n)                                      \
  asm volatile("s_waitcnt vmcnt(" #n ")" ::: "memory");   \
  __builtin_amdgcn_s_barrier();                           \
  __builtin_amdgcn_sched_barrier(0);

template <bool SWAP>
__device__ __forceinline__ void gemm_core32q(const u16* __restrict__ A, const u16* __restrict__ Bt,
                                             int row0, int col0, u16* As, u16* Bs, f32x16 acc[2][2]) {
  const int tid = threadIdx.x, w = tid >> 6, lane = tid & 63;
  const int l31 = lane & 31, hi = lane >> 5;
  const int wm = (w >> 1) * 64, wn = (w & 1) * 64;

  // Staging source pre-swizzle (R2-verified byte-space form for BK=32 rows).
  int r_[2], c_[2];
#pragma unroll
  for (int i = 0; i < 2; i++) {
    int X = (w * 2 + i) * 1024 + lane * 16;           // byte offset within one buffer
    int e = (X ^ (((X >> 7) & 7) << 4)) >> 1;         // swizzled element index
    r_[i] = e >> 5;
    c_[i] = e & 31;
  }
  // Frag read offsets (elements), swizzled; loop-invariant.
  int oa[2][2], ob[2][2];
#pragma unroll
  for (int t = 0; t < 2; t++)
#pragma unroll
    for (int s = 0; s < 2; s++) {
      int Pa = (wm + t * 32 + l31) * 64 + s * 32 + hi * 16;
      int Pb = (wn + t * 32 + l31) * 64 + s * 32 + hi * 16;
      oa[t][s] = (Pa ^ (((Pa >> 7) & 7) << 4)) >> 1;
      ob[t][s] = (Pb ^ (((Pb >> 7) & 7) << 4)) >> 1;
    }

  const u16* Ag = A + (size_t)row0 * 1024;
  const u16* Bg = Bt + (size_t)col0 * 1024;

#define PIPE_ISSUE(k2)                                                              \
  {                                                                                 \
    u16* Ad = As + ((k2) & 3) * 4096 + (w * 2) * 512;                               \
    u16* Bd = Bs + ((k2) & 3) * 4096 + (w * 2) * 512;                               \
    _Pragma("unroll") for (int i = 0; i < 2; i++) {                                 \
      GLOAD_LDS16(Ag + (size_t)r_[i] * 1024 + (k2) * 32 + c_[i], Ad + i * 512);     \
      GLOAD_LDS16(Bg + (size_t)r_[i] * 1024 + (k2) * 32 + c_[i], Bd + i * 512);     \
    }                                                                               \
  }

#define PIPE_COMPUTE(it)                                                            \
  {                                                                                 \
    const u16* Ab = As + ((it) & 3) * 4096;                                         \
    const u16* Bb = Bs + ((it) & 3) * 4096;                                         \
    bf16x8 af[2][2], bfr[2][2];                                                     \
    _Pragma("unroll") for (int t = 0; t < 2; t++)                                   \
      _Pragma("unroll") for (int s = 0; s < 2; s++) {                               \
        af[t][s] = ldfrag(Ab + oa[t][s]);                                           \
        bfr[t][s] = ldfrag(Bb + ob[t][s]);                                          \
      }                                                                             \
    __builtin_amdgcn_s_setprio(1);                                                  \
    _Pragma("unroll") for (int mt = 0; mt < 2; mt++)                                \
      _Pragma("unroll") for (int nt = 0; nt < 2; nt++)                              \
        _Pragma("unroll") for (int s = 0; s < 2; s++)                               \
          acc[mt][nt] = SWAP ? MFMA32(bfr[nt][s], af[mt][s], acc[mt][nt])           \
                             : MFMA32(af[mt][s], bfr[nt][s], acc[mt][nt]);          \
    __builtin_amdgcn_s_setprio(0);                                                  \
  }

  // Prologue: issue steps 0 and 1.
  PIPE_ISSUE(0);
  PIPE_ISSUE(1);
  // Main loop: iters 0..29 — issue it+2, wait vmcnt(8) (drains it's loads), compute.
  for (int it = 0; it < 30; ++it) {
    PIPE_ISSUE(it + 2);
    PIPE_WAIT(8)
    PIPE_COMPUTE(it);
  }
  // Epilogue: iters 30 (only 31's loads may remain in flight) and 31.
  PIPE_WAIT(4)
  PIPE_COMPUTE(30);
  PIPE_WAIT(0)
  PIPE_COMPUTE(31);

#undef PIPE_ISSUE
#undef PIPE_COMPUTE
}

// ---------------- GEMM1: qkv projection (Q pre-scaled by QSC) ----------------

__global__ __launch_bounds__(256) void k_gemm_qkv(const u16* __restrict__ xb, const u16* __restrict__ wt,
                                                  const float* __restrict__ bq, const float* __restrict__ bk,
                                                  const float* __restrict__ bv,
                                                  u16* __restrict__ qo, u16* __restrict__ ko,
                                                  u16* __restrict__ vto) {
  __shared__ u16 As[16384], Bs[16384];
  f32x16 acc[2][2];
#pragma unroll
  for (int a = 0; a < 2; a++)
#pragma unroll
    for (int b = 0; b < 2; b++)
#pragma unroll
      for (int r = 0; r < 16; r++) acc[a][b][r] = 0.f;

  const int row0 = blockIdx.x * 128, col0 = blockIdx.y * 128;
  const int p = blockIdx.y >> 3;
  const int colr = (blockIdx.y & 7) * 128;
  const int tid = threadIdx.x, w = tid >> 6, lane = tid & 63;
  const int l31 = lane & 31, hi = lane >> 5;
  const int wm = (w >> 1) * 64, wn = (w & 1) * 64;

  if (p == 2) {
    gemm_core32q<true>(xb, wt, row0, col0, As, Bs, acc);
#pragma unroll
    for (int mt = 0; mt < 2; mt++) {
      int rb = row0 + wm + mt * 32;
      int b_ = rb >> 11;
      int s_ = (rb & 2047) + l31;
#pragma unroll
      for (int nt = 0; nt < 2; nt++) {
        int ebase = colr + wn + nt * 32;
#pragma unroll
        for (int g = 0; g < 4; g++) {
          float4 bvv = *(const float4*)(bv + ebase + g * 8 + hi * 4);
#pragma unroll
          for (int j = 0; j < 4; j++) {
            int rem = ebase + g * 8 + hi * 4 + j;
            int h = rem >> 6, e = rem & 63;
            float val = acc[mt][nt][g * 4 + j] + (&bvv.x)[j];
            vto[(((size_t)(b_ * 16 + h)) * 64 + e) * 2048 + s_] = f2b(val);
          }
        }
      }
    }
  } else {
    gemm_core32q<false>(xb, wt, row0, col0, As, Bs, acc);
    u16* dst = (p == 0) ? qo : ko;
    const float* bias = (p == 0) ? bq : bk;
    const float qsc = (p == 0) ? QSC : 1.0f;
#pragma unroll
    for (int nt = 0; nt < 2; nt++) {
      int rem = colr + wn + nt * 32 + l31;
      int h = rem >> 6, e = rem & 63;
      float bval = bias[rem];
#pragma unroll
      for (int mt = 0; mt < 2; mt++) {
        int rb = row0 + wm + mt * 32;
        int b_ = rb >> 11, sb = rb & 2047;
        size_t obase = ((size_t)(b_ * 16 + h) * 2048) * 64 + e;
#pragma unroll
        for (int reg = 0; reg < 16; reg++) {
          int s_ = sb + (reg & 3) + 8 * (reg >> 2) + 4 * hi;
          float val = (acc[mt][nt][reg] + bval) * qsc;
          dst[obase + (size_t)s_ * 64] = f2b(val);
        }
      }
    }
  }
}

// ---------------- GEMM2: output projection (MFMA32, fp32 out) ----------------

__global__ __launch_bounds__(256) void k_gemm_out(const u16* __restrict__ zb, const u16* __restrict__ wt,
                                                  const float* __restrict__ bo, float* __restrict__ out) {
  __shared__ u16 As[16384], Bs[16384];
  f32x16 acc[2][2];
#pragma unroll
  for (int a = 0; a < 2; a++)
#pragma unroll
    for (int b = 0; b < 2; b++)
#pragma unroll
      for (int r = 0; r < 16; r++) acc[a][b][r] = 0.f;

  const int row0 = blockIdx.x * 128, col0 = blockIdx.y * 128;
  gemm_core32q<false>(zb, wt, row0, col0, As, Bs, acc);

  const int tid = threadIdx.x, w = tid >> 6, lane = tid & 63;
  const int l31 = lane & 31, hi = lane >> 5;
  const int wm = (w >> 1) * 64, wn = (w & 1) * 64;
#pragma unroll
  for (int nt = 0; nt < 2; nt++) {
    int c = col0 + wn + nt * 32 + l31;
    float bval = bo[c];
#pragma unroll
    for (int mt = 0; mt < 2; mt++) {
      int rb = row0 + wm + mt * 32;
#pragma unroll
      for (int reg = 0; reg < 16; reg++) {
        int r = rb + (reg & 3) + 8 * (reg >> 2) + 4 * hi;
        out[(size_t)r * 1024 + c] = acc[mt][nt][reg] + bval;
      }
    }
  }
}

// ---------------- flash attention v10 = v6b + XCD-local grid (measured optimum) ----------
// UNCHANGED from R12 (87.8us reproduced; VGPR 124, zero headroom — see ledger).

__global__ __launch_bounds__(256, 2) void k_attn(const u16* __restrict__ q, const u16* __restrict__ k,
                                                 const u16* __restrict__ vt, u16* __restrict__ z) {
  __shared__ u16 Ks[2][64 * 72], Vs[2][64 * 72];
  const int tid = threadIdx.x, w = tid >> 6, lane = tid & 63;
  const int l31 = lane & 31, hi = lane >> 5;
  const int bh = blockIdx.x, s0 = blockIdx.y * 256;  // XCD-local: bh on gridDim.x=64
  const size_t base = (size_t)bh * 2048 * 64;
  const int qrow0 = s0 + w * 64;

  bf16x8 qf[2][4];
#pragma unroll
  for (int u = 0; u < 2; u++) {
    const u16* qp = q + base + (size_t)(qrow0 + u * 32 + l31) * 64 + hi * 8;
#pragma unroll
    for (int ks = 0; ks < 4; ks++) qf[u][ks] = ldfrag(qp + ks * 16);
  }

  f32x16 accT[2][2];
  float ls[2] = {0.f, 0.f};
#pragma unroll
  for (int u = 0; u < 2; u++)
#pragma unroll
    for (int r = 0; r < 16; r++) { accT[u][0][r] = 0.f; accT[u][1][r] = 0.f; }

  const int srow = tid >> 3;
  const int scol = (tid & 7) * 8;
  const u16* kg = k + base;
  const u16* vg = vt + base;

  u32x4 kr0 = *(const u32x4*)(kg + (size_t)srow * 64 + scol);
  u32x4 kr1 = *(const u32x4*)(kg + (size_t)(srow + 32) * 64 + scol);
  u32x4 vr0 = *(const u32x4*)(vg + (size_t)srow * 2048 + scol);
  u32x4 vr1 = *(const u32x4*)(vg + (size_t)(srow + 32) * 2048 + scol);
  *(u32x4*)&Ks[0][srow * 72 + scol] = kr0;
  *(u32x4*)&Ks[0][(srow + 32) * 72 + scol] = kr1;
  *(u32x4*)&Vs[0][srow * 72 + scol] = vr0;
  *(u32x4*)&Vs[0][(srow + 32) * 72 + scol] = vr1;
  kr0 = *(const u32x4*)(kg + (size_t)(64 + srow) * 64 + scol);
  kr1 = *(const u32x4*)(kg + (size_t)(64 + srow + 32) * 64 + scol);
  vr0 = *(const u32x4*)(vg + (size_t)srow * 2048 + 64 + scol);
  vr1 = *(const u32x4*)(vg + (size_t)(srow + 32) * 2048 + 64 + scol);
  __syncthreads();

  for (int kc = 0; kc < 2048; kc += 64) {
    const int buf = (kc >> 6) & 1;
    const u16* Kb = &Ks[buf][0];
    const u16* Vb = &Vs[buf][0];

    bf16x8 pf[2][4];
#pragma unroll
    for (int t = 0; t < 2; t++) {
      f32x16 scA, scB;
#pragma unroll
      for (int r = 0; r < 16; r++) { scA[r] = 0.f; scB[r] = 0.f; }
      __builtin_amdgcn_s_setprio(1);
#pragma unroll
      for (int ks = 0; ks < 4; ks++) {
        bf16x8 kf = ldfrag(Kb + (t * 32 + l31) * 72 + ks * 16 + hi * 8);
        scA = MFMA32(kf, qf[0][ks], scA);
        scB = MFMA32(kf, qf[1][ks], scB);
      }
      __builtin_amdgcn_s_setprio(0);
#pragma unroll
      for (int r = 0; r < 16; r++) scA[r] = fexp2(scA[r]);
#pragma unroll
      for (int r = 0; r < 16; r++) scB[r] = fexp2(scB[r]);
      ls[0] += sum16(scA);
      ls[1] += sum16(scB);
      build_frags(scA, pf[0][2 * t], pf[0][2 * t + 1]);
      build_frags(scB, pf[1][2 * t], pf[1][2 * t + 1]);
    }

    if (kc + 64 < 2048) {
      *(u32x4*)&Ks[buf ^ 1][srow * 72 + scol] = kr0;
      *(u32x4*)&Ks[buf ^ 1][(srow + 32) * 72 + scol] = kr1;
      *(u32x4*)&Vs[buf ^ 1][srow * 72 + scol] = vr0;
      *(u32x4*)&Vs[buf ^ 1][(srow + 32) * 72 + scol] = vr1;
      if (kc + 128 < 2048) {
        int kn = kc + 128;
        kr0 = *(const u32x4*)(kg + (size_t)(kn + srow) * 64 + scol);
        kr1 = *(const u32x4*)(kg + (size_t)(kn + srow + 32) * 64 + scol);
        vr0 = *(const u32x4*)(vg + (size_t)srow * 2048 + kn + scol);
        vr1 = *(const u32x4*)(vg + (size_t)(srow + 32) * 2048 + kn + scol);
      }
    }

    __builtin_amdgcn_s_setprio(1);
#pragma unroll
    for (int ks = 0; ks < 4; ks++) {
      bf16x8 vf0 = ldfrag(Vb + (0 * 32 + l31) * 72 + ks * 16 + hi * 8);
      bf16x8 vf1 = ldfrag(Vb + (1 * 32 + l31) * 72 + ks * 16 + hi * 8);
      accT[0][0] = MFMA32(vf0, pf[0][ks], accT[0][0]);
      accT[0][1] = MFMA32(vf1, pf[0][ks], accT[0][1]);
      accT[1][0] = MFMA32(vf0, pf[1][ks], accT[1][0]);
      accT[1][1] = MFMA32(vf1, pf[1][ks], accT[1][1]);
    }
    __builtin_amdgcn_s_setprio(0);
    __syncthreads();
  }

  const int b_ = bh >> 4, h = bh & 15;
#pragma unroll
  for (int u = 0; u < 2; u++) {
    float l = ls[u];
    l += __shfl_xor(l, 32);
    float inv = 1.f / l;
    int qrow = qrow0 + u * 32 + l31;
    u16* zr = z + ((size_t)(b_ * 2048 + qrow)) * 1024 + h * 64;
#pragma unroll
    for (int et = 0; et < 2; et++)
#pragma unroll
      for (int rr = 0; rr < 16; rr += 2) {
        unsigned pkd = pkbf(accT[u][et][rr] * inv, accT[u][et][rr + 1] * inv);
        int e = et * 32 + (rr & 3) + 8 * (rr >> 2) + 4 * hi;
        *(unsigned*)&zr[e] = pkd;
      }
  }
}

// ---------------- launcher ----------------

extern "C" void kernel_launch(void* const* d_in, const int* in_sizes, int n_in,
                              void* d_out, int out_size, void* d_ws, size_t ws_size,
                              hipStream_t stream) {
  (void)in_sizes; (void)n_in; (void)out_size;
  const float* x  = (const float*)d_in[0];
  const float* Wq = (const float*)d_in[1];
  const float* bq = (const float*)d_in[2];
  const float* Wk = (const float*)d_in[3];
  const float* bk = (const float*)d_in[4];
  const float* Wv = (const float*)d_in[5];
  const float* bv = (const float*)d_in[6];
  const float* Wo = (const float*)d_in[7];
  const float* bo = (const float*)d_in[8];
  float* out = (float*)d_out;
  char* ws = (char*)d_ws;
  if (ws_size < 92274688u) return;  // need ~92 MB scratch

  u16* xb   = (u16*)(ws + 0);          // 8192x1024 bf16          (16 MiB)
  u16* wqkv = (u16*)(ws + 16777216);   // 3072x1024 bf16 (Bt)     (6 MiB)
  u16* wo_t = (u16*)(ws + 23068672);   // 1024x1024 bf16 (Bt)     (2 MiB)
  u16* qb   = (u16*)(ws + 25165824);   // [bh][s][e] (q * QSC)    (16 MiB)
  u16* kb   = (u16*)(ws + 41943040);   // [bh][s][e]              (16 MiB)
  u16* vtb  = (u16*)(ws + 58720256);   // [bh][e][s]              (16 MiB)
  u16* zb   = (u16*)(ws + 75497472);   // multi_head [8192][1024] (16 MiB)

  k_pack<<<5120, 256, 0, stream>>>(x, Wq, Wk, Wv, Wo, xb, wqkv, wo_t);
  k_gemm_qkv<<<dim3(64, 24), 256, 0, stream>>>(xb, wqkv, bq, bk, bv, qb, kb, vtb);
  k_attn<<<dim3(64, 8), 256, 0, stream>>>(qb, kb, vtb, zb);  // (bh, qtile): bh%8 pins XCD
  k_gemm_out<<<dim3(64, 8), 256, 0, stream>>>(zb, wo_t, bo, out);
}

// Round 14
// 260.316 us; speedup vs baseline: 1.1024x; 1.1024x over previous
//
#include <hip/hip_runtime.h>

typedef unsigned short u16;
typedef __bf16 bf16x8 __attribute__((ext_vector_type(8)));
typedef float f32x4 __attribute__((ext_vector_type(4)));
typedef float f32x16 __attribute__((ext_vector_type(16)));
typedef unsigned int u32x4 __attribute__((ext_vector_type(4)));
typedef unsigned int u32x2 __attribute__((ext_vector_type(2)));

__device__ __forceinline__ u16 f2b(float f) {
  union { float f; unsigned u; } v; v.f = f;
  return (u16)((v.u + 0x7fffu + ((v.u >> 16) & 1u)) >> 16);
}

__device__ __forceinline__ unsigned pkbf(float a, float b) {
#if __has_builtin(__builtin_amdgcn_cvt_pk_bf16_f32)
  typedef __bf16 bf16x2v __attribute__((ext_vector_type(2)));
  bf16x2v r = __builtin_amdgcn_cvt_pk_bf16_f32(a, b);
  return __builtin_bit_cast(unsigned, r);
#else
  // round-half-up (vs RNE: differs only on exact ties, <=1 ulp) + byte-perm pack: 3 VALU ops
  unsigned ua = __builtin_bit_cast(unsigned, a) + 0x8000u;
  unsigned ub = __builtin_bit_cast(unsigned, b) + 0x8000u;
  return __builtin_amdgcn_perm(ub, ua, 0x07060302u);
#endif
}

__device__ __forceinline__ float fexp2(float x) {
#if __has_builtin(__builtin_amdgcn_exp2f)
  return __builtin_amdgcn_exp2f(x);
#else
  return exp2f(x);
#endif
}

__device__ __forceinline__ bf16x8 ldfrag(const u16* p) {
  u32x4 r = *(const u32x4*)p;
  return __builtin_bit_cast(bf16x8, r);
}

// v_permlane32_swap_b32 dst, src: post dst = [dst_lo ; src_lo], src = [dst_hi ; src_hi].
__device__ __forceinline__ void plswap(unsigned& dst, unsigned& src) {
  asm("v_permlane32_swap_b32 %0, %1" : "+v"(dst), "+v"(src));
}

__device__ __forceinline__ float sum16(const f32x16& v) {
  float a = (v[0] + v[1]) + (v[2] + v[3]);
  float b = (v[4] + v[5]) + (v[6] + v[7]);
  float c = (v[8] + v[9]) + (v[10] + v[11]);
  float d = (v[12] + v[13]) + (v[14] + v[15]);
  return (a + b) + (c + d);
}

// T12: S^T C/D regs (key=(r&3)+8*(r>>2)+4*hi, q=l31) -> PV B-operand frags
// (key=ks*16+hi*8+j, q=l31) fully in-register.
__device__ __forceinline__ void build_frags(const f32x16& sc, bf16x8& fLo, bf16x8& fHi) {
  unsigned a0 = pkbf(sc[0], sc[1]);
  unsigned a1 = pkbf(sc[2], sc[3]);
  unsigned b0 = pkbf(sc[4], sc[5]);
  unsigned b1 = pkbf(sc[6], sc[7]);
  plswap(a0, b0);  // a0 = word0, b0 = word2
  plswap(a1, b1);  // a1 = word1, b1 = word3
  u32x4 f; f[0] = a0; f[1] = a1; f[2] = b0; f[3] = b1;
  fLo = __builtin_bit_cast(bf16x8, f);
  unsigned c0 = pkbf(sc[8], sc[9]);
  unsigned c1 = pkbf(sc[10], sc[11]);
  unsigned d0 = pkbf(sc[12], sc[13]);
  unsigned d1 = pkbf(sc[14], sc[15]);
  plswap(c0, d0);
  plswap(c1, d1);
  u32x4 g; g[0] = c0; g[1] = c1; g[2] = d0; g[3] = d1;
  fHi = __builtin_bit_cast(bf16x8, g);
}

#define GLOAD_LDS16(gp, lp)                                                        \
  __builtin_amdgcn_global_load_lds((const __attribute__((address_space(1))) void*)(gp), \
                                   (__attribute__((address_space(3))) void*)(lp), 16, 0, 0)

#define MFMA32(a, b, c) __builtin_amdgcn_mfma_f32_32x32x16_bf16((a), (b), (c), 0, 0, 0)

// 0.125 * log2(e): folded into Q during GEMM1 (no-max softmax in exp2 domain).
#define QSC 0.18033688011f

// ---------------- merged pack kernel ----------------

__global__ __launch_bounds__(256) void k_pack(const float* __restrict__ x,
                                              const float* __restrict__ Wq,
                                              const float* __restrict__ Wk,
                                              const float* __restrict__ Wv,
                                              const float* __restrict__ Wo,
                                              u16* __restrict__ xb,
                                              u16* __restrict__ wqkv,
                                              u16* __restrict__ wo_t) {
  const int bid = blockIdx.x, tid = threadIdx.x;
  if (bid < 4096) {
    int i = (bid * 256 + tid) * 8;
    float4 v0 = *(const float4*)(x + i);
    float4 v1 = *(const float4*)(x + i + 4);
    u32x4 o;
    o[0] = pkbf(v0.x, v0.y);
    o[1] = pkbf(v0.z, v0.w);
    o[2] = pkbf(v1.x, v1.y);
    o[3] = pkbf(v1.z, v1.w);
    *(u32x4*)(xb + i) = o;
    return;
  }
  __shared__ u16 tile[64][65];
  if (bid < 4864) {
    int b2 = bid - 4096;
    int p = b2 >> 8, rem = b2 & 255, h = rem >> 4, dt = rem & 15;
    const float* W = (p == 0) ? Wq : (p == 1) ? Wk : Wv;
    for (int i = tid; i < 4096; i += 256) {
      int d = i >> 6, e = i & 63;
      tile[e][d] = f2b(W[h * 65536 + (dt * 64 + d) * 64 + e]);
    }
    __syncthreads();
    for (int i = tid; i < 4096; i += 256) {
      int e = i >> 6, d = i & 63;
      wqkv[(size_t)(p * 1024 + h * 64 + e) * 1024 + dt * 64 + d] = tile[e][d];
    }
  } else {
    int b2 = bid - 4864;
    int kt = b2 >> 4, nt = b2 & 15;
    for (int i = tid; i < 4096; i += 256) {
      int dk = i >> 6, de = i & 63;
      tile[de][dk] = f2b(Wo[(size_t)(kt * 64 + dk) * 1024 + nt * 64 + de]);
    }
    __syncthreads();
    for (int i = tid; i < 4096; i += 256) {
      int de = i >> 6, dk = i & 63;
      wo_t[(size_t)(nt * 64 + de) * 1024 + kt * 64 + dk] = tile[de][dk];
    }
  }
}

// ---------------- GEMM core v3 (MFMA32): 128x128 tile, BK=64, K=1024 ----------------
// BK=64: 32 MFMA per barrier, half the barrier/drain fixed cost vs BK=32 (R7: -14us).
// T2 swizzle in ELEMENT space: SWZ(P) = P ^ (((P>>7)&7)<<3) (involution); LDS dest linear
// for gload_lds, global SOURCE pre-permuted, frag reads swizzled.
// R13 post-mortem: counted-vmcnt 4-deep graft (BK=32, raw s_barrier + vmcnt(8) +
// sched_barrier(0)) REGRESSED +17us total — reproduces guide m131/m141: fine vmcnt at
// HIP source is neutral-to-negative without the full 8-phase role-split; sched_barrier
// pinning defeats compiler scheduling. This simple BK=64 dbuf is the measured optimum.
// NOTE: do NOT add a second __launch_bounds__ arg (R5: waves-per-eu=4 budgeted the
// 64-reg boundary and spilled acc => 186us).

template <bool SWAP>
__device__ __forceinline__ void gemm_core64(const u16* __restrict__ A, const u16* __restrict__ Bt,
                                            int row0, int col0, u16* As, u16* Bs, f32x16 acc[2][2]) {
  const int tid = threadIdx.x, w = tid >> 6, lane = tid & 63;
  const int l31 = lane & 31, hi = lane >> 5;
  const int wm = (w >> 1) * 64, wn = (w & 1) * 64;

  int r_[4], c_[4];
#pragma unroll
  for (int i = 0; i < 4; i++) {
    int E = (w * 4 + i) * 512 + lane * 8;
    int e = E ^ (((E >> 7) & 7) << 3);
    r_[i] = e >> 6;
    c_[i] = e & 63;
  }
  int oa[2][2][2], ob[2][2][2];  // [kh][t][s]
#pragma unroll
  for (int kh = 0; kh < 2; kh++)
#pragma unroll
    for (int t = 0; t < 2; t++)
#pragma unroll
      for (int s = 0; s < 2; s++) {
        int Pa = (wm + t * 32 + l31) * 64 + kh * 32 + s * 16 + hi * 8;
        int Pb = (wn + t * 32 + l31) * 64 + kh * 32 + s * 16 + hi * 8;
        oa[kh][t][s] = Pa ^ (((Pa >> 7) & 7) << 3);
        ob[kh][t][s] = Pb ^ (((Pb >> 7) & 7) << 3);
      }

  const u16* Ag = A + (size_t)row0 * 1024;
  const u16* Bg = Bt + (size_t)col0 * 1024;

#pragma unroll
  for (int i = 0; i < 4; i++) {
    GLOAD_LDS16(Ag + (size_t)r_[i] * 1024 + c_[i], As + (w * 4 + i) * 512);
    GLOAD_LDS16(Bg + (size_t)r_[i] * 1024 + c_[i], Bs + (w * 4 + i) * 512);
  }
  __syncthreads();  // implicit vmcnt(0) drain

  int cur = 0;
  for (int k0 = 0; k0 < 1024; k0 += 64) {
    if (k0 + 64 < 1024) {
      u16* Ad = As + (cur ^ 1) * 8192 + (w * 4) * 512;
      u16* Bd = Bs + (cur ^ 1) * 8192 + (w * 4) * 512;
#pragma unroll
      for (int i = 0; i < 4; i++) {
        GLOAD_LDS16(Ag + (size_t)r_[i] * 1024 + k0 + 64 + c_[i], Ad + i * 512);
        GLOAD_LDS16(Bg + (size_t)r_[i] * 1024 + k0 + 64 + c_[i], Bd + i * 512);
      }
    }
    const u16* Ab = As + cur * 8192;
    const u16* Bb = Bs + cur * 8192;
#pragma unroll
    for (int kh = 0; kh < 2; kh++) {
      bf16x8 af[2][2], bfr[2][2];
#pragma unroll
      for (int t = 0; t < 2; t++)
#pragma unroll
        for (int s = 0; s < 2; s++) {
          af[t][s] = ldfrag(Ab + oa[kh][t][s]);
          bfr[t][s] = ldfrag(Bb + ob[kh][t][s]);
        }
      __builtin_amdgcn_s_setprio(1);
#pragma unroll
      for (int mt = 0; mt < 2; mt++)
#pragma unroll
        for (int nt = 0; nt < 2; nt++)
#pragma unroll
          for (int s = 0; s < 2; s++)
            acc[mt][nt] = SWAP ? MFMA32(bfr[nt][s], af[mt][s], acc[mt][nt])
                               : MFMA32(af[mt][s], bfr[nt][s], acc[mt][nt]);
      __builtin_amdgcn_s_setprio(0);
    }
    __syncthreads();
    cur ^= 1;
  }
}

// ---------------- GEMM1: qkv projection (Q pre-scaled by QSC) ----------------

__global__ __launch_bounds__(256) void k_gemm_qkv(const u16* __restrict__ xb, const u16* __restrict__ wt,
                                                  const float* __restrict__ bq, const float* __restrict__ bk,
                                                  const float* __restrict__ bv,
                                                  u16* __restrict__ qo, u16* __restrict__ ko,
                                                  u16* __restrict__ vto) {
  __shared__ u16 As[16384], Bs[16384];
  f32x16 acc[2][2];
#pragma unroll
  for (int a = 0; a < 2; a++)
#pragma unroll
    for (int b = 0; b < 2; b++)
#pragma unroll
      for (int r = 0; r < 16; r++) acc[a][b][r] = 0.f;

  const int row0 = blockIdx.x * 128, col0 = blockIdx.y * 128;
  const int p = blockIdx.y >> 3;
  const int colr = (blockIdx.y & 7) * 128;
  const int tid = threadIdx.x, w = tid >> 6, lane = tid & 63;
  const int l31 = lane & 31, hi = lane >> 5;
  const int wm = (w >> 1) * 64, wn = (w & 1) * 64;

  if (p == 2) {
    gemm_core64<true>(xb, wt, row0, col0, As, Bs, acc);
#pragma unroll
    for (int mt = 0; mt < 2; mt++) {
      int rb = row0 + wm + mt * 32;
      int b_ = rb >> 11;
      int s_ = (rb & 2047) + l31;
#pragma unroll
      for (int nt = 0; nt < 2; nt++) {
        int ebase = colr + wn + nt * 32;
#pragma unroll
        for (int g = 0; g < 4; g++) {
          float4 bvv = *(const float4*)(bv + ebase + g * 8 + hi * 4);
#pragma unroll
          for (int j = 0; j < 4; j++) {
            int rem = ebase + g * 8 + hi * 4 + j;
            int h = rem >> 6, e = rem & 63;
            float val = acc[mt][nt][g * 4 + j] + (&bvv.x)[j];
            vto[(((size_t)(b_ * 16 + h)) * 64 + e) * 2048 + s_] = f2b(val);
          }
        }
      }
    }
  } else {
    gemm_core64<false>(xb, wt, row0, col0, As, Bs, acc);
    u16* dst = (p == 0) ? qo : ko;
    const float* bias = (p == 0) ? bq : bk;
    const float qsc = (p == 0) ? QSC : 1.0f;
#pragma unroll
    for (int nt = 0; nt < 2; nt++) {
      int rem = colr + wn + nt * 32 + l31;
      int h = rem >> 6, e = rem & 63;
      float bval = bias[rem];
#pragma unroll
      for (int mt = 0; mt < 2; mt++) {
        int rb = row0 + wm + mt * 32;
        int b_ = rb >> 11, sb = rb & 2047;
        size_t obase = ((size_t)(b_ * 16 + h) * 2048) * 64 + e;
#pragma unroll
        for (int reg = 0; reg < 16; reg++) {
          int s_ = sb + (reg & 3) + 8 * (reg >> 2) + 4 * hi;
          float val = (acc[mt][nt][reg] + bval) * qsc;
          dst[obase + (size_t)s_ * 64] = f2b(val);
        }
      }
    }
  }
}

// ---------------- GEMM2: output projection (MFMA32, fp32 out) ----------------

__global__ __launch_bounds__(256) void k_gemm_out(const u16* __restrict__ zb, const u16* __restrict__ wt,
                                                  const float* __restrict__ bo, float* __restrict__ out) {
  __shared__ u16 As[16384], Bs[16384];
  f32x16 acc[2][2];
#pragma unroll
  for (int a = 0; a < 2; a++)
#pragma unroll
    for (int b = 0; b < 2; b++)
#pragma unroll
      for (int r = 0; r < 16; r++) acc[a][b][r] = 0.f;

  const int row0 = blockIdx.x * 128, col0 = blockIdx.y * 128;
  gemm_core64<false>(zb, wt, row0, col0, As, Bs, acc);

  const int tid = threadIdx.x, w = tid >> 6, lane = tid & 63;
  const int l31 = lane & 31, hi = lane >> 5;
  const int wm = (w >> 1) * 64, wn = (w & 1) * 64;
#pragma unroll
  for (int nt = 0; nt < 2; nt++) {
    int c = col0 + wn + nt * 32 + l31;
    float bval = bo[c];
#pragma unroll
    for (int mt = 0; mt < 2; mt++) {
      int rb = row0 + wm + mt * 32;
#pragma unroll
      for (int reg = 0; reg < 16; reg++) {
        int r = rb + (reg & 3) + 8 * (reg >> 2) + 4 * hi;
        out[(size_t)r * 1024 + c] = acc[mt][nt][reg] + bval;
      }
    }
  }
}

// ---------------- flash attention v10 = v6b + XCD-local grid (measured optimum) ----------
// Perturbation ledger (all reverted): occupancy up (R5/R6) worse; ones-MFMA denom (R8)
// worse; V-hoist (R9) spill; gload_lds/KVBLK128 (R11) spill; GEMM counted-vmcnt (R13)
// worse. 88us attn / 270us total is the stable measured optimum of this structure.

__global__ __launch_bounds__(256, 2) void k_attn(const u16* __restrict__ q, const u16* __restrict__ k,
                                                 const u16* __restrict__ vt, u16* __restrict__ z) {
  __shared__ u16 Ks[2][64 * 72], Vs[2][64 * 72];
  const int tid = threadIdx.x, w = tid >> 6, lane = tid & 63;
  const int l31 = lane & 31, hi = lane >> 5;
  const int bh = blockIdx.x, s0 = blockIdx.y * 256;  // XCD-local: bh on gridDim.x=64
  const size_t base = (size_t)bh * 2048 * 64;
  const int qrow0 = s0 + w * 64;

  bf16x8 qf[2][4];
#pragma unroll
  for (int u = 0; u < 2; u++) {
    const u16* qp = q + base + (size_t)(qrow0 + u * 32 + l31) * 64 + hi * 8;
#pragma unroll
    for (int ks = 0; ks < 4; ks++) qf[u][ks] = ldfrag(qp + ks * 16);
  }

  f32x16 accT[2][2];
  float ls[2] = {0.f, 0.f};
#pragma unroll
  for (int u = 0; u < 2; u++)
#pragma unroll
    for (int r = 0; r < 16; r++) { accT[u][0][r] = 0.f; accT[u][1][r] = 0.f; }

  const int srow = tid >> 3;
  const int scol = (tid & 7) * 8;
  const u16* kg = k + base;
  const u16* vg = vt + base;

  u32x4 kr0 = *(const u32x4*)(kg + (size_t)srow * 64 + scol);
  u32x4 kr1 = *(const u32x4*)(kg + (size_t)(srow + 32) * 64 + scol);
  u32x4 vr0 = *(const u32x4*)(vg + (size_t)srow * 2048 + scol);
  u32x4 vr1 = *(const u32x4*)(vg + (size_t)(srow + 32) * 2048 + scol);
  *(u32x4*)&Ks[0][srow * 72 + scol] = kr0;
  *(u32x4*)&Ks[0][(srow + 32) * 72 + scol] = kr1;
  *(u32x4*)&Vs[0][srow * 72 + scol] = vr0;
  *(u32x4*)&Vs[0][(srow + 32) * 72 + scol] = vr1;
  kr0 = *(const u32x4*)(kg + (size_t)(64 + srow) * 64 + scol);
  kr1 = *(const u32x4*)(kg + (size_t)(64 + srow + 32) * 64 + scol);
  vr0 = *(const u32x4*)(vg + (size_t)srow * 2048 + 64 + scol);
  vr1 = *(const u32x4*)(vg + (size_t)(srow + 32) * 2048 + 64 + scol);
  __syncthreads();

  for (int kc = 0; kc < 2048; kc += 64) {
    const int buf = (kc >> 6) & 1;
    const u16* Kb = &Ks[buf][0];
    const u16* Vb = &Vs[buf][0];

    bf16x8 pf[2][4];
#pragma unroll
    for (int t = 0; t < 2; t++) {
      f32x16 scA, scB;
#pragma unroll
      for (int r = 0; r < 16; r++) { scA[r] = 0.f; scB[r] = 0.f; }
      __builtin_amdgcn_s_setprio(1);
#pragma unroll
      for (int ks = 0; ks < 4; ks++) {
        bf16x8 kf = ldfrag(Kb + (t * 32 + l31) * 72 + ks * 16 + hi * 8);
        scA = MFMA32(kf, qf[0][ks], scA);
        scB = MFMA32(kf, qf[1][ks], scB);
      }
      __builtin_amdgcn_s_setprio(0);
#pragma unroll
      for (int r = 0; r < 16; r++) scA[r] = fexp2(scA[r]);
#pragma unroll
      for (int r = 0; r < 16; r++) scB[r] = fexp2(scB[r]);
      ls[0] += sum16(scA);
      ls[1] += sum16(scB);
      build_frags(scA, pf[0][2 * t], pf[0][2 * t + 1]);
      build_frags(scB, pf[1][2 * t], pf[1][2 * t + 1]);
    }

    if (kc + 64 < 2048) {
      *(u32x4*)&Ks[buf ^ 1][srow * 72 + scol] = kr0;
      *(u32x4*)&Ks[buf ^ 1][(srow + 32) * 72 + scol] = kr1;
      *(u32x4*)&Vs[buf ^ 1][srow * 72 + scol] = vr0;
      *(u32x4*)&Vs[buf ^ 1][(srow + 32) * 72 + scol] = vr1;
      if (kc + 128 < 2048) {
        int kn = kc + 128;
        kr0 = *(const u32x4*)(kg + (size_t)(kn + srow) * 64 + scol);
        kr1 = *(const u32x4*)(kg + (size_t)(kn + srow + 32) * 64 + scol);
        vr0 = *(const u32x4*)(vg + (size_t)srow * 2048 + kn + scol);
        vr1 = *(const u32x4*)(vg + (size_t)(srow + 32) * 2048 + kn + scol);
      }
    }

    __builtin_amdgcn_s_setprio(1);
#pragma unroll
    for (int ks = 0; ks < 4; ks++) {
      bf16x8 vf0 = ldfrag(Vb + (0 * 32 + l31) * 72 + ks * 16 + hi * 8);
      bf16x8 vf1 = ldfrag(Vb + (1 * 32 + l31) * 72 + ks * 16 + hi * 8);
      accT[0][0] = MFMA32(vf0, pf[0][ks], accT[0][0]);
      accT[0][1] = MFMA32(vf1, pf[0][ks], accT[0][1]);
      accT[1][0] = MFMA32(vf0, pf[1][ks], accT[1][0]);
      accT[1][1] = MFMA32(vf1, pf[1][ks], accT[1][1]);
    }
    __builtin_amdgcn_s_setprio(0);
    __syncthreads();
  }

  const int b_ = bh >> 4, h = bh & 15;
#pragma unroll
  for (int u = 0; u < 2; u++) {
    float l = ls[u];
    l += __shfl_xor(l, 32);
    float inv = 1.f / l;
    int qrow = qrow0 + u * 32 + l31;
    u16* zr = z + ((size_t)(b_ * 2048 + qrow)) * 1024 + h * 64;
#pragma unroll
    for (int et = 0; et < 2; et++)
#pragma unroll
      for (int rr = 0; rr < 16; rr += 2) {
        unsigned pkd = pkbf(accT[u][et][rr] * inv, accT[u][et][rr + 1] * inv);
        int e = et * 32 + (rr & 3) + 8 * (rr >> 2) + 4 * hi;
        *(unsigned*)&zr[e] = pkd;
      }
  }
}

// ---------------- launcher ----------------

extern "C" void kernel_launch(void* const* d_in, const int* in_sizes, int n_in,
                              void* d_out, int out_size, void* d_ws, size_t ws_size,
                              hipStream_t stream) {
  (void)in_sizes; (void)n_in; (void)out_size;
  const float* x  = (const float*)d_in[0];
  const float* Wq = (const float*)d_in[1];
  const float* bq = (const float*)d_in[2];
  const float* Wk = (const float*)d_in[3];
  const float* bk = (const float*)d_in[4];
  const float* Wv = (const float*)d_in[5];
  const float* bv = (const float*)d_in[6];
  const float* Wo = (const float*)d_in[7];
  const float* bo = (const float*)d_in[8];
  float* out = (float*)d_out;
  char* ws = (char*)d_ws;
  if (ws_size < 92274688u) return;  // need ~92 MB scratch

  u16* xb   = (u16*)(ws + 0);          // 8192x1024 bf16          (16 MiB)
  u16* wqkv = (u16*)(ws + 16777216);   // 3072x1024 bf16 (Bt)     (6 MiB)
  u16* wo_t = (u16*)(ws + 23068672);   // 1024x1024 bf16 (Bt)     (2 MiB)
  u16* qb   = (u16*)(ws + 25165824);   // [bh][s][e] (q * QSC)    (16 MiB)
  u16* kb   = (u16*)(ws + 41943040);   // [bh][s][e]              (16 MiB)
  u16* vtb  = (u16*)(ws + 58720256);   // [bh][e][s]              (16 MiB)
  u16* zb   = (u16*)(ws + 75497472);   // multi_head [8192][1024] (16 MiB)

  k_pack<<<5120, 256, 0, stream>>>(x, Wq, Wk, Wv, Wo, xb, wqkv, wo_t);
  k_gemm_qkv<<<dim3(64, 24), 256, 0, stream>>>(xb, wqkv, bq, bk, bv, qb, kb, vtb);
  k_attn<<<dim3(64, 8), 256, 0, stream>>>(qb, kb, vtb, zb);  // (bh, qtile): bh%8 pins XCD
  k_gemm_out<<<dim3(64, 8), 256, 0, stream>>>(zb, wo_t, bo, out);
}